// Round 1
// baseline (154.573 us; speedup 1.0000x reference)
//
#include <hip/hip_runtime.h>
#include <hip/hip_bf16.h>
#include <math.h>

// Problem constants (from reference): N=4, E=64, L=512, D=768
#define PN 4
#define PE 64
#define PL 512
#define PD 768
#define PK2 (2 * PD)        // 1536
#define PM (PN * PE)        // 256 rows

// ---------------------------------------------------------------------------
// Kernel 1: masked max/mean pooling.
// One block per (n,e) pair. 256 threads; thread t owns d = t, t+256, t+512.
// entity_states[n,e,l,d] = mask[n,e,l] * doc[n,l,d];
//   max over l  -> includes 0 whenever any mask entry is 0 (has_zero)
//   sum over l / lens[n,e]
// P layout: [256][1536], first 768 = max, last 768 = mean.
// ---------------------------------------------------------------------------
__global__ __launch_bounds__(256) void pool_kernel(
    const float* __restrict__ doc,    // [N][L][D]
    const float* __restrict__ map,    // [N][E][L]
    const float* __restrict__ lens,   // [N][E]
    float* __restrict__ P)            // [M][2D]
{
    const int ne = blockIdx.x;        // 0..255
    const int n  = ne >> 6;           // / E
    const int t  = threadIdx.x;

    const float* docn = doc + (size_t)n * PL * PD;
    const float* mrow = map + (size_t)ne * PL;

    float mx0 = -INFINITY, mx1 = -INFINITY, mx2 = -INFINITY;
    float s0 = 0.f, s1 = 0.f, s2 = 0.f;
    bool  has_zero = false;

    for (int l = 0; l < PL; ++l) {
        const float m = mrow[l];           // same addr all lanes -> broadcast
        if (m != 0.0f) {                   // block-uniform branch
            const float* dr = docn + (size_t)l * PD;
            const float a = dr[t];
            const float c = dr[t + 256];
            const float e = dr[t + 512];
            mx0 = fmaxf(mx0, a); s0 += a;
            mx1 = fmaxf(mx1, c); s1 += c;
            mx2 = fmaxf(mx2, e); s2 += e;
        } else {
            has_zero = true;
        }
    }
    if (has_zero) {                        // 0-mask rows contribute 0 to max
        mx0 = fmaxf(mx0, 0.f);
        mx1 = fmaxf(mx1, 0.f);
        mx2 = fmaxf(mx2, 0.f);
    }
    const float invlen = 1.0f / lens[ne];

    float* prow = P + (size_t)ne * PK2;
    prow[t]        = mx0;
    prow[t + 256]  = mx1;
    prow[t + 512]  = mx2;
    prow[PD + t]       = s0 * invlen;
    prow[PD + t + 256] = s1 * invlen;
    prow[PD + t + 512] = s2 * invlen;
}

// ---------------------------------------------------------------------------
// Kernel 2: C[r,d] = sum_k P[r,k] * W[d,k] + b[d]
// M=256, N=768, K=1536. Tiled: BM=32, BN=64, BK=32, 256 threads,
// each thread computes 2 rows x 4 cols. Grid (8, 12).
// ---------------------------------------------------------------------------
#define BM 32
#define BN 64
#define BK 32

__global__ __launch_bounds__(256) void gemm_kernel(
    const float* __restrict__ P,   // [256][1536]
    const float* __restrict__ W,   // [768][1536]
    const float* __restrict__ b,   // [768]
    float* __restrict__ out)       // [256][768]
{
    __shared__ float Pt[BM][BK + 1];
    __shared__ float Wt[BK][BN + 1];   // transposed: [k][col]

    const int tid  = threadIdx.x;
    const int row0 = blockIdx.x * BM;
    const int col0 = blockIdx.y * BN;

    const int tx = tid & 15;      // 16 col groups (4 cols each)
    const int ty = tid >> 4;      // 16 row groups (2 rows each)

    float acc[2][4] = {{0.f, 0.f, 0.f, 0.f}, {0.f, 0.f, 0.f, 0.f}};

    for (int k0 = 0; k0 < PK2; k0 += BK) {
        // ---- load P tile: 32x32 = 1024 floats, one float4 per thread
        {
            const int r = tid >> 3;              // (tid*4)/32
            const int c = (tid & 7) << 2;        // (tid*4)%32
            const float4 v = *reinterpret_cast<const float4*>(
                &P[(size_t)(row0 + r) * PK2 + k0 + c]);
            Pt[r][c + 0] = v.x; Pt[r][c + 1] = v.y;
            Pt[r][c + 2] = v.z; Pt[r][c + 3] = v.w;
        }
        // ---- load W tile (transposed into LDS): 64x32 = 2048 floats, 2 float4/thread
        #pragma unroll
        for (int i = 0; i < 2; ++i) {
            const int e = tid + i * 256;         // 0..511
            const int d = e >> 3;                // (e*4)/32
            const int c = (e & 7) << 2;          // (e*4)%32
            const float4 v = *reinterpret_cast<const float4*>(
                &W[(size_t)(col0 + d) * PK2 + k0 + c]);
            Wt[c + 0][d] = v.x; Wt[c + 1][d] = v.y;
            Wt[c + 2][d] = v.z; Wt[c + 3][d] = v.w;
        }
        __syncthreads();

        #pragma unroll
        for (int kk = 0; kk < BK; ++kk) {
            const float a0 = Pt[ty * 2 + 0][kk];
            const float a1 = Pt[ty * 2 + 1][kk];
            const float w0 = Wt[kk][tx * 4 + 0];
            const float w1 = Wt[kk][tx * 4 + 1];
            const float w2 = Wt[kk][tx * 4 + 2];
            const float w3 = Wt[kk][tx * 4 + 3];
            acc[0][0] += a0 * w0; acc[0][1] += a0 * w1;
            acc[0][2] += a0 * w2; acc[0][3] += a0 * w3;
            acc[1][0] += a1 * w0; acc[1][1] += a1 * w1;
            acc[1][2] += a1 * w2; acc[1][3] += a1 * w3;
        }
        __syncthreads();
    }

    #pragma unroll
    for (int i = 0; i < 2; ++i) {
        const int r = row0 + ty * 2 + i;
        #pragma unroll
        for (int j = 0; j < 4; ++j) {
            const int d = col0 + tx * 4 + j;
            out[(size_t)r * PD + d] = acc[i][j] + b[d];
        }
    }
}

// ---------------------------------------------------------------------------
// Fallback: fully fused (used only if ws_size is too small for P).
// One block per (n,e): pool into LDS, then 3 dot products per thread.
// ---------------------------------------------------------------------------
__global__ __launch_bounds__(256) void fused_kernel(
    const float* __restrict__ doc,
    const float* __restrict__ map,
    const float* __restrict__ lens,
    const float* __restrict__ W,
    const float* __restrict__ b,
    float* __restrict__ out)
{
    __shared__ float Prow[PK2];

    const int ne = blockIdx.x;
    const int n  = ne >> 6;
    const int t  = threadIdx.x;

    const float* docn = doc + (size_t)n * PL * PD;
    const float* mrow = map + (size_t)ne * PL;

    float mx0 = -INFINITY, mx1 = -INFINITY, mx2 = -INFINITY;
    float s0 = 0.f, s1 = 0.f, s2 = 0.f;
    bool  has_zero = false;

    for (int l = 0; l < PL; ++l) {
        const float m = mrow[l];
        if (m != 0.0f) {
            const float* dr = docn + (size_t)l * PD;
            const float a = dr[t];
            const float c = dr[t + 256];
            const float e = dr[t + 512];
            mx0 = fmaxf(mx0, a); s0 += a;
            mx1 = fmaxf(mx1, c); s1 += c;
            mx2 = fmaxf(mx2, e); s2 += e;
        } else {
            has_zero = true;
        }
    }
    if (has_zero) {
        mx0 = fmaxf(mx0, 0.f);
        mx1 = fmaxf(mx1, 0.f);
        mx2 = fmaxf(mx2, 0.f);
    }
    const float invlen = 1.0f / lens[ne];
    Prow[t]        = mx0;
    Prow[t + 256]  = mx1;
    Prow[t + 512]  = mx2;
    Prow[PD + t]       = s0 * invlen;
    Prow[PD + t + 256] = s1 * invlen;
    Prow[PD + t + 512] = s2 * invlen;
    __syncthreads();

    #pragma unroll
    for (int i = 0; i < 3; ++i) {
        const int d = t + i * 256;
        const float* wrow = W + (size_t)d * PK2;
        float acc = 0.f;
        for (int k = 0; k < PK2; k += 4) {
            const float4 w = *reinterpret_cast<const float4*>(&wrow[k]);
            acc += Prow[k] * w.x + Prow[k + 1] * w.y +
                   Prow[k + 2] * w.z + Prow[k + 3] * w.w;
        }
        out[(size_t)ne * PD + d] = acc + b[d];
    }
}

extern "C" void kernel_launch(void* const* d_in, const int* in_sizes, int n_in,
                              void* d_out, int out_size, void* d_ws, size_t ws_size,
                              hipStream_t stream) {
    const float* doc  = (const float*)d_in[0];   // (4,512,768)
    const float* map  = (const float*)d_in[1];   // (4,64,512)
    const float* lens = (const float*)d_in[2];   // (4,64)
    const float* W    = (const float*)d_in[3];   // (768,1536)
    const float* b    = (const float*)d_in[4];   // (768,)
    float* out = (float*)d_out;                  // (4,64,768)

    const size_t p_bytes = (size_t)PM * PK2 * sizeof(float);   // 1.57 MB

    if (ws_size >= p_bytes) {
        float* P = (float*)d_ws;
        pool_kernel<<<dim3(PM), dim3(256), 0, stream>>>(doc, map, lens, P);
        gemm_kernel<<<dim3(PM / BM, PD / BN), dim3(256), 0, stream>>>(P, W, b, out);
    } else {
        fused_kernel<<<dim3(PM), dim3(256), 0, stream>>>(doc, map, lens, W, b, out);
    }
}

// Round 2
// 66.600 us; speedup vs baseline: 2.3209x; 2.3209x over previous
//
#include <hip/hip_runtime.h>
#include <hip/hip_bf16.h>
#include <math.h>

// Problem constants: N=4, E=64, L=512, D=768
#define PN 4
#define PE 64
#define PL 512
#define PD 768
#define PK2 (2 * PD)        // 1536
#define PM (PN * PE)        // 256 rows

using bf16x8 = __attribute__((ext_vector_type(8))) short;
using f32x4  = __attribute__((ext_vector_type(4))) float;

static __device__ __forceinline__ unsigned short f2bf(float x) {
    unsigned int u = __float_as_uint(x);
    unsigned int r = (u + 0x7FFFu + ((u >> 16) & 1u)) >> 16;   // RNE
    return (unsigned short)r;
}

// ---------------------------------------------------------------------------
// W (f32 [768][1536]) -> bf16. 8 elems/thread, 576 blocks x 256.
// ---------------------------------------------------------------------------
__global__ __launch_bounds__(256) void convert_w(
    const float* __restrict__ W, unsigned short* __restrict__ Wb)
{
    const size_t i = ((size_t)blockIdx.x * 256 + threadIdx.x) * 8;
    const float4 a = *reinterpret_cast<const float4*>(W + i);
    const float4 c = *reinterpret_cast<const float4*>(W + i + 4);
    union { unsigned short s[8]; uint4 v; } r;
    r.s[0] = f2bf(a.x); r.s[1] = f2bf(a.y); r.s[2] = f2bf(a.z); r.s[3] = f2bf(a.w);
    r.s[4] = f2bf(c.x); r.s[5] = f2bf(c.y); r.s[6] = f2bf(c.z); r.s[7] = f2bf(c.w);
    *reinterpret_cast<uint4*>(Wb + i) = r.v;
}

// ---------------------------------------------------------------------------
// Pooling v2: one block per (n,e), 1024 threads = 4 L-groups x 256 d-threads.
// Group g handles l in [g*128, g*128+128); thread owns d = td, td+256, td+512.
// Partials reduced via LDS. Emits P directly as bf16 [256][1536]
// (first 768 = max, last 768 = mean).
// ---------------------------------------------------------------------------
__global__ __launch_bounds__(1024) void pool_kernel2(
    const float* __restrict__ doc,    // [N][L][D]
    const float* __restrict__ map,    // [N][E][L]
    const float* __restrict__ lens,   // [N][E]
    unsigned short* __restrict__ Pb)  // [M][2D] bf16
{
    __shared__ float psum[4][PD];
    __shared__ float pmax[4][PD];
    __shared__ int   zf[4];

    const int ne = blockIdx.x;
    const int n  = ne >> 6;
    const int t  = threadIdx.x;
    const int g  = t >> 8;            // L-group 0..3
    const int td = t & 255;

    const float* docn = doc + (size_t)n * PL * PD;
    const float* mrow = map + (size_t)ne * PL;

    float mx0 = -INFINITY, mx1 = -INFINITY, mx2 = -INFINITY;
    float s0 = 0.f, s1 = 0.f, s2 = 0.f;
    bool  hz = false;

    const int l0 = g * (PL / 4), l1 = l0 + (PL / 4);
    for (int l = l0; l < l1; ++l) {
        const float m = mrow[l];          // wave-uniform broadcast
        if (m != 0.0f) {                  // block(-group)-uniform branch
            const float* dr = docn + (size_t)l * PD;
            const float a = dr[td];
            const float c = dr[td + 256];
            const float e = dr[td + 512];
            mx0 = fmaxf(mx0, a); s0 += a;
            mx1 = fmaxf(mx1, c); s1 += c;
            mx2 = fmaxf(mx2, e); s2 += e;
        } else {
            hz = true;
        }
    }
    psum[g][td]       = s0;  pmax[g][td]       = mx0;
    psum[g][td + 256] = s1;  pmax[g][td + 256] = mx1;
    psum[g][td + 512] = s2;  pmax[g][td + 512] = mx2;
    if (td == 0) zf[g] = hz ? 1 : 0;      // hz uniform within group
    __syncthreads();

    if (t < PD) {
        const float s  = psum[0][t] + psum[1][t] + psum[2][t] + psum[3][t];
        float       mx = fmaxf(fmaxf(pmax[0][t], pmax[1][t]),
                               fmaxf(pmax[2][t], pmax[3][t]));
        if (zf[0] | zf[1] | zf[2] | zf[3]) mx = fmaxf(mx, 0.f);
        const float invlen = 1.0f / lens[ne];
        unsigned short* prow = Pb + (size_t)ne * PK2;
        prow[t]      = f2bf(mx);
        prow[PD + t] = f2bf(s * invlen);
    }
}

// ---------------------------------------------------------------------------
// GEMM via MFMA bf16 16x16x32, no LDS (everything L2-resident).
// out[r][d] = sum_k P[r][k] * W[d][k] + b[d]   (gemm_bt pattern)
// 768 output tiles of 16x16; 4 waves/block -> 192 blocks.
// A-frag: lane holds P[r0+(lane&15)][k0 + (lane>>4)*8 + j]  (16B contiguous)
// B-frag: lane holds W[d0+(lane&15)][k0 + (lane>>4)*8 + j]  (16B contiguous)
// D:      col = lane&15 (n), row = (lane>>4)*4 + j (m)      [m89/m91]
// ---------------------------------------------------------------------------
__global__ __launch_bounds__(256) void gemm_mfma(
    const unsigned short* __restrict__ Pb,  // [256][1536] bf16
    const unsigned short* __restrict__ Wb,  // [768][1536] bf16
    const float* __restrict__ b,            // [768]
    float* __restrict__ out)                // [256][768]
{
    const int w    = threadIdx.x >> 6;
    const int lane = threadIdx.x & 63;
    const int tile = blockIdx.x * 4 + w;     // 0..767
    const int rt = tile & 15;                // 16 row tiles (M)
    const int ct = tile >> 4;                // 48 col tiles (N) — block's 4 waves share ct mostly
    const int r0 = rt * 16, d0 = ct * 16;

    const int fr = lane & 15;                // fragment row
    const int kg = lane >> 4;                // k-group 0..3

    const unsigned short* pA = Pb + (size_t)(r0 + fr) * PK2 + kg * 8;
    const unsigned short* pB = Wb + (size_t)(d0 + fr) * PK2 + kg * 8;

    f32x4 acc = {0.f, 0.f, 0.f, 0.f};
    #pragma unroll 8
    for (int k0 = 0; k0 < PK2; k0 += 32) {
        const bf16x8 a  = *reinterpret_cast<const bf16x8*>(pA + k0);
        const bf16x8 bb = *reinterpret_cast<const bf16x8*>(pB + k0);
        acc = __builtin_amdgcn_mfma_f32_16x16x32_bf16(a, bb, acc, 0, 0, 0);
    }

    const int c = d0 + fr;
    const float bias = b[c];
    #pragma unroll
    for (int j = 0; j < 4; ++j) {
        const int r = r0 + kg * 4 + j;
        out[(size_t)r * PD + c] = acc[j] + bias;
    }
}

// ===========================================================================
// Fallback f32 path (proven correct in R1) — used if ws is too small.
// ===========================================================================
__global__ __launch_bounds__(256) void pool_kernel(
    const float* __restrict__ doc, const float* __restrict__ map,
    const float* __restrict__ lens, float* __restrict__ P)
{
    const int ne = blockIdx.x;
    const int n  = ne >> 6;
    const int t  = threadIdx.x;
    const float* docn = doc + (size_t)n * PL * PD;
    const float* mrow = map + (size_t)ne * PL;
    float mx0 = -INFINITY, mx1 = -INFINITY, mx2 = -INFINITY;
    float s0 = 0.f, s1 = 0.f, s2 = 0.f;
    bool  has_zero = false;
    for (int l = 0; l < PL; ++l) {
        const float m = mrow[l];
        if (m != 0.0f) {
            const float* dr = docn + (size_t)l * PD;
            const float a = dr[t];
            const float c = dr[t + 256];
            const float e = dr[t + 512];
            mx0 = fmaxf(mx0, a); s0 += a;
            mx1 = fmaxf(mx1, c); s1 += c;
            mx2 = fmaxf(mx2, e); s2 += e;
        } else has_zero = true;
    }
    if (has_zero) { mx0 = fmaxf(mx0, 0.f); mx1 = fmaxf(mx1, 0.f); mx2 = fmaxf(mx2, 0.f); }
    const float invlen = 1.0f / lens[ne];
    float* prow = P + (size_t)ne * PK2;
    prow[t] = mx0; prow[t + 256] = mx1; prow[t + 512] = mx2;
    prow[PD + t] = s0 * invlen; prow[PD + t + 256] = s1 * invlen; prow[PD + t + 512] = s2 * invlen;
}

#define BM 32
#define BN 64
#define BK 32
__global__ __launch_bounds__(256) void gemm_kernel(
    const float* __restrict__ P, const float* __restrict__ W,
    const float* __restrict__ b, float* __restrict__ out)
{
    __shared__ float Pt[BM][BK + 1];
    __shared__ float Wt[BK][BN + 1];
    const int tid  = threadIdx.x;
    const int row0 = blockIdx.x * BM;
    const int col0 = blockIdx.y * BN;
    const int tx = tid & 15, ty = tid >> 4;
    float acc[2][4] = {{0,0,0,0},{0,0,0,0}};
    for (int k0 = 0; k0 < PK2; k0 += BK) {
        {
            const int r = tid >> 3, c = (tid & 7) << 2;
            const float4 v = *reinterpret_cast<const float4*>(&P[(size_t)(row0 + r) * PK2 + k0 + c]);
            Pt[r][c] = v.x; Pt[r][c+1] = v.y; Pt[r][c+2] = v.z; Pt[r][c+3] = v.w;
        }
        #pragma unroll
        for (int i = 0; i < 2; ++i) {
            const int e = tid + i * 256, d = e >> 3, c = (e & 7) << 2;
            const float4 v = *reinterpret_cast<const float4*>(&W[(size_t)(col0 + d) * PK2 + k0 + c]);
            Wt[c][d] = v.x; Wt[c+1][d] = v.y; Wt[c+2][d] = v.z; Wt[c+3][d] = v.w;
        }
        __syncthreads();
        #pragma unroll
        for (int kk = 0; kk < BK; ++kk) {
            const float a0 = Pt[ty*2][kk], a1 = Pt[ty*2+1][kk];
            const float w0 = Wt[kk][tx*4], w1 = Wt[kk][tx*4+1];
            const float w2 = Wt[kk][tx*4+2], w3 = Wt[kk][tx*4+3];
            acc[0][0]+=a0*w0; acc[0][1]+=a0*w1; acc[0][2]+=a0*w2; acc[0][3]+=a0*w3;
            acc[1][0]+=a1*w0; acc[1][1]+=a1*w1; acc[1][2]+=a1*w2; acc[1][3]+=a1*w3;
        }
        __syncthreads();
    }
    #pragma unroll
    for (int i = 0; i < 2; ++i) {
        const int r = row0 + ty*2 + i;
        #pragma unroll
        for (int j = 0; j < 4; ++j)
            out[(size_t)r * PD + col0 + tx*4 + j] = acc[i][j] + b[col0 + tx*4 + j];
    }
}

__global__ __launch_bounds__(256) void fused_kernel(
    const float* __restrict__ doc, const float* __restrict__ map,
    const float* __restrict__ lens, const float* __restrict__ W,
    const float* __restrict__ b, float* __restrict__ out)
{
    __shared__ float Prow[PK2];
    const int ne = blockIdx.x, n = ne >> 6, t = threadIdx.x;
    const float* docn = doc + (size_t)n * PL * PD;
    const float* mrow = map + (size_t)ne * PL;
    float mx0=-INFINITY, mx1=-INFINITY, mx2=-INFINITY, s0=0.f, s1=0.f, s2=0.f;
    bool has_zero = false;
    for (int l = 0; l < PL; ++l) {
        const float m = mrow[l];
        if (m != 0.0f) {
            const float* dr = docn + (size_t)l * PD;
            const float a = dr[t], c = dr[t+256], e = dr[t+512];
            mx0=fmaxf(mx0,a); s0+=a; mx1=fmaxf(mx1,c); s1+=c; mx2=fmaxf(mx2,e); s2+=e;
        } else has_zero = true;
    }
    if (has_zero) { mx0=fmaxf(mx0,0.f); mx1=fmaxf(mx1,0.f); mx2=fmaxf(mx2,0.f); }
    const float invlen = 1.0f / lens[ne];
    Prow[t]=mx0; Prow[t+256]=mx1; Prow[t+512]=mx2;
    Prow[PD+t]=s0*invlen; Prow[PD+t+256]=s1*invlen; Prow[PD+t+512]=s2*invlen;
    __syncthreads();
    #pragma unroll
    for (int i = 0; i < 3; ++i) {
        const int d = t + i*256;
        const float* wrow = W + (size_t)d * PK2;
        float acc = 0.f;
        for (int k = 0; k < PK2; k += 4) {
            const float4 w = *reinterpret_cast<const float4*>(&wrow[k]);
            acc += Prow[k]*w.x + Prow[k+1]*w.y + Prow[k+2]*w.z + Prow[k+3]*w.w;
        }
        out[(size_t)ne * PD + d] = acc + b[d];
    }
}

extern "C" void kernel_launch(void* const* d_in, const int* in_sizes, int n_in,
                              void* d_out, int out_size, void* d_ws, size_t ws_size,
                              hipStream_t stream) {
    const float* doc  = (const float*)d_in[0];   // (4,512,768)
    const float* map  = (const float*)d_in[1];   // (4,64,512)
    const float* lens = (const float*)d_in[2];   // (4,64)
    const float* W    = (const float*)d_in[3];   // (768,1536)
    const float* b    = (const float*)d_in[4];   // (768,)
    float* out = (float*)d_out;                  // (4,64,768)

    const size_t pb_bytes = (size_t)PM * PK2 * sizeof(unsigned short);   // 768 KB
    const size_t wb_bytes = (size_t)PD * PK2 * sizeof(unsigned short);   // 2.25 MiB
    const size_t need_bf16 = pb_bytes + wb_bytes;                        // 3 MiB
    const size_t p_bytes = (size_t)PM * PK2 * sizeof(float);             // 1.5 MiB

    if (ws_size >= need_bf16) {
        unsigned short* Pb = (unsigned short*)d_ws;
        unsigned short* Wb = (unsigned short*)((char*)d_ws + pb_bytes);
        convert_w<<<dim3((PD * PK2) / (256 * 8)), dim3(256), 0, stream>>>(W, Wb);
        pool_kernel2<<<dim3(PM), dim3(1024), 0, stream>>>(doc, map, lens, Pb);
        gemm_mfma<<<dim3((PM / 16) * (PD / 16) / 4), dim3(256), 0, stream>>>(Pb, Wb, b, out);
    } else if (ws_size >= p_bytes) {
        float* P = (float*)d_ws;
        pool_kernel<<<dim3(PM), dim3(256), 0, stream>>>(doc, map, lens, P);
        gemm_kernel<<<dim3(PM / BM, PD / BN), dim3(256), 0, stream>>>(P, W, b, out);
    } else {
        fused_kernel<<<dim3(PM), dim3(256), 0, stream>>>(doc, map, lens, W, b, out);
    }
}

// Round 3
// 47.786 us; speedup vs baseline: 3.2347x; 1.3937x over previous
//
#include <hip/hip_runtime.h>
#include <hip/hip_bf16.h>
#include <math.h>

// Problem constants: N=4, E=64, L=512, D=768
#define PN 4
#define PE 64
#define PL 512
#define PD 768
#define PK2 (2 * PD)        // 1536
#define PM (PN * PE)        // 256 rows

#define SPL 8               // L splits (chunks of 64)
#define EG  8               // entities per pool block

using bf16x8 = __attribute__((ext_vector_type(8))) short;
using f32x4  = __attribute__((ext_vector_type(4))) float;

static __device__ __forceinline__ unsigned short f2bf(float x) {
    unsigned int u = __float_as_uint(x);
    unsigned int r = (u + 0x7FFFu + ((u >> 16) & 1u)) >> 16;   // RNE
    return (unsigned short)r;
}

// ---------------------------------------------------------------------------
// pool_p1 (+ fused W->bf16 convert in extra blocks).
// Pool blocks (bid 0..255): (n, e-group of 8, L-chunk of 64).
//   256 threads; thread owns d = td, td+256, td+512.
//   Mask chunk staged in LDS as {m, bias}; bias = (m==0) ? -3e38 : 0 so
//   masked max candidate = fma(m, v, bias)  (branch-free).
//   Writes partial max/sum: Pmax/Psum [ne][s][d]  (each 256*8*768 f32).
// Convert blocks (bid 256..831): W f32 -> Wb bf16, 8 elems/thread.
// ---------------------------------------------------------------------------
__global__ __launch_bounds__(256) void pool_p1(
    const float* __restrict__ doc,    // [N][L][D]
    const float* __restrict__ map,    // [N][E][L]
    const float* __restrict__ W,      // [768][1536]
    float* __restrict__ Pmax,         // [256][8][768]
    float* __restrict__ Psum,         // [256][8][768]
    unsigned short* __restrict__ Wb)  // [768][1536] bf16
{
    const int bid = blockIdx.x;
    const int tid = threadIdx.x;

    if (bid >= PM) {
        // ---- W conversion blocks ----
        const size_t i = ((size_t)(bid - PM) * 256 + tid) * 8;
        const float4 a = *reinterpret_cast<const float4*>(W + i);
        const float4 c = *reinterpret_cast<const float4*>(W + i + 4);
        union { unsigned short s[8]; uint4 v; } r;
        r.s[0] = f2bf(a.x); r.s[1] = f2bf(a.y); r.s[2] = f2bf(a.z); r.s[3] = f2bf(a.w);
        r.s[4] = f2bf(c.x); r.s[5] = f2bf(c.y); r.s[6] = f2bf(c.z); r.s[7] = f2bf(c.w);
        *reinterpret_cast<uint4*>(Wb + i) = r.v;
        return;
    }

    __shared__ float2 smb[EG][64];    // {m, bias} per (e, l-in-chunk)

    const int n  = bid >> 6;          // / 64
    const int eg = (bid >> 3) & 7;
    const int s  = bid & 7;
    const int e0 = eg * EG;
    const int l0 = s * 64;

    // stage mask chunk: 8 e x 64 l = 512 entries, 2 per thread
    #pragma unroll
    for (int i = 0; i < 2; ++i) {
        const int idx = tid + i * 256;
        const int e = idx >> 6, l = idx & 63;
        const float m = map[((size_t)n * PE + e0 + e) * PL + l0 + l];
        smb[e][l] = make_float2(m, (m == 0.0f) ? -3.0e38f : 0.0f);
    }
    __syncthreads();

    const float* docn = doc + ((size_t)n * PL + l0) * PD;

    float mx[EG][3], sm[EG][3];
    #pragma unroll
    for (int e = 0; e < EG; ++e)
        #pragma unroll
        for (int j = 0; j < 3; ++j) { mx[e][j] = -INFINITY; sm[e][j] = 0.f; }

    for (int l = 0; l < 64; ++l) {
        const float v0 = docn[(size_t)l * PD + tid];
        const float v1 = docn[(size_t)l * PD + tid + 256];
        const float v2 = docn[(size_t)l * PD + tid + 512];
        #pragma unroll
        for (int e = 0; e < EG; ++e) {
            const float2 mb = smb[e][l];
            sm[e][0] = fmaf(mb.x, v0, sm[e][0]);
            sm[e][1] = fmaf(mb.x, v1, sm[e][1]);
            sm[e][2] = fmaf(mb.x, v2, sm[e][2]);
            mx[e][0] = fmaxf(mx[e][0], fmaf(mb.x, v0, mb.y));
            mx[e][1] = fmaxf(mx[e][1], fmaf(mb.x, v1, mb.y));
            mx[e][2] = fmaxf(mx[e][2], fmaf(mb.x, v2, mb.y));
        }
    }

    #pragma unroll
    for (int e = 0; e < EG; ++e) {
        const size_t base = ((size_t)(n * PE + e0 + e) * SPL + s) * PD;
        #pragma unroll
        for (int j = 0; j < 3; ++j) {
            Pmax[base + tid + j * 256] = mx[e][j];
            Psum[base + tid + j * 256] = sm[e][j];
        }
    }
}

// ---------------------------------------------------------------------------
// pool_p2: fold 8 L-chunk partials -> Pb bf16 [256][1536] (max | mean).
// has_zero for entity (n,e) <=> lens < 512 (lens is exact mask sum, >=1).
// 768 blocks x 256 threads, one (ne,d) per thread.
// ---------------------------------------------------------------------------
__global__ __launch_bounds__(256) void pool_p2(
    const float* __restrict__ Pmax,
    const float* __restrict__ Psum,
    const float* __restrict__ lens,   // [256]
    unsigned short* __restrict__ Pb)  // [256][1536]
{
    const int idx = blockIdx.x * 256 + threadIdx.x;   // 0..196607
    const int ne = idx / PD;
    const int d  = idx - ne * PD;

    float mx = -INFINITY, smv = 0.f;
    #pragma unroll
    for (int s = 0; s < SPL; ++s) {
        const size_t o = ((size_t)ne * SPL + s) * PD + d;
        mx  = fmaxf(mx, Pmax[o]);
        smv += Psum[o];
    }
    const float ln = lens[ne];
    if (ln < 511.5f) mx = fmaxf(mx, 0.f);   // some mask entry is 0

    unsigned short* prow = Pb + (size_t)ne * PK2;
    prow[d]      = f2bf(mx);
    prow[PD + d] = f2bf(smv / ln);
}

// ---------------------------------------------------------------------------
// GEMM via MFMA bf16 16x16x32, no LDS. out[r][d] = sum_k P[r][k]*W[d][k] + b[d]
// 768 single-wave blocks, one 16x16 tile each.
// ---------------------------------------------------------------------------
__global__ __launch_bounds__(64) void gemm_mfma(
    const unsigned short* __restrict__ Pb,  // [256][1536] bf16
    const unsigned short* __restrict__ Wb,  // [768][1536] bf16
    const float* __restrict__ b,            // [768]
    float* __restrict__ out)                // [256][768]
{
    const int lane = threadIdx.x;
    const int tile = blockIdx.x;             // 0..767
    const int rt = tile & 15;                // M tile
    const int ct = tile >> 4;                // N tile
    const int r0 = rt * 16, d0 = ct * 16;

    const int fr = lane & 15;
    const int kg = lane >> 4;

    const unsigned short* pA = Pb + (size_t)(r0 + fr) * PK2 + kg * 8;
    const unsigned short* pB = Wb + (size_t)(d0 + fr) * PK2 + kg * 8;

    f32x4 acc = {0.f, 0.f, 0.f, 0.f};
    #pragma unroll 8
    for (int k0 = 0; k0 < PK2; k0 += 32) {
        const bf16x8 a  = *reinterpret_cast<const bf16x8*>(pA + k0);
        const bf16x8 bb = *reinterpret_cast<const bf16x8*>(pB + k0);
        acc = __builtin_amdgcn_mfma_f32_16x16x32_bf16(a, bb, acc, 0, 0, 0);
    }

    const int c = d0 + fr;
    const float bias = b[c];
    #pragma unroll
    for (int j = 0; j < 4; ++j)
        out[(size_t)(r0 + kg * 4 + j) * PD + c] = acc[j] + bias;
}

// ===========================================================================
// Fallback path (R2, proven): pool_kernel2 + convert_w + gemm (3 MiB ws)
// ===========================================================================
__global__ __launch_bounds__(256) void convert_w(
    const float* __restrict__ W, unsigned short* __restrict__ Wb)
{
    const size_t i = ((size_t)blockIdx.x * 256 + threadIdx.x) * 8;
    const float4 a = *reinterpret_cast<const float4*>(W + i);
    const float4 c = *reinterpret_cast<const float4*>(W + i + 4);
    union { unsigned short s[8]; uint4 v; } r;
    r.s[0] = f2bf(a.x); r.s[1] = f2bf(a.y); r.s[2] = f2bf(a.z); r.s[3] = f2bf(a.w);
    r.s[4] = f2bf(c.x); r.s[5] = f2bf(c.y); r.s[6] = f2bf(c.z); r.s[7] = f2bf(c.w);
    *reinterpret_cast<uint4*>(Wb + i) = r.v;
}

__global__ __launch_bounds__(1024) void pool_kernel2(
    const float* __restrict__ doc, const float* __restrict__ map,
    const float* __restrict__ lens, unsigned short* __restrict__ Pb)
{
    __shared__ float psum[4][PD];
    __shared__ float pmax[4][PD];
    __shared__ int   zf[4];
    const int ne = blockIdx.x, n = ne >> 6, t = threadIdx.x;
    const int g = t >> 8, td = t & 255;
    const float* docn = doc + (size_t)n * PL * PD;
    const float* mrow = map + (size_t)ne * PL;
    float mx0=-INFINITY, mx1=-INFINITY, mx2=-INFINITY, s0=0.f, s1=0.f, s2=0.f;
    bool hz = false;
    const int l0 = g * (PL/4), l1 = l0 + (PL/4);
    for (int l = l0; l < l1; ++l) {
        const float m = mrow[l];
        if (m != 0.0f) {
            const float* dr = docn + (size_t)l * PD;
            const float a = dr[td], c = dr[td+256], e = dr[td+512];
            mx0=fmaxf(mx0,a); s0+=a; mx1=fmaxf(mx1,c); s1+=c; mx2=fmaxf(mx2,e); s2+=e;
        } else hz = true;
    }
    psum[g][td]=s0; pmax[g][td]=mx0;
    psum[g][td+256]=s1; pmax[g][td+256]=mx1;
    psum[g][td+512]=s2; pmax[g][td+512]=mx2;
    if (td == 0) zf[g] = hz ? 1 : 0;
    __syncthreads();
    if (t < PD) {
        const float s = psum[0][t]+psum[1][t]+psum[2][t]+psum[3][t];
        float mx = fmaxf(fmaxf(pmax[0][t],pmax[1][t]), fmaxf(pmax[2][t],pmax[3][t]));
        if (zf[0]|zf[1]|zf[2]|zf[3]) mx = fmaxf(mx, 0.f);
        const float invlen = 1.0f / lens[ne];
        unsigned short* prow = Pb + (size_t)ne * PK2;
        prow[t]      = f2bf(mx);
        prow[PD + t] = f2bf(s * invlen);
    }
}

__global__ __launch_bounds__(256) void fused_kernel(
    const float* __restrict__ doc, const float* __restrict__ map,
    const float* __restrict__ lens, const float* __restrict__ W,
    const float* __restrict__ b, float* __restrict__ out)
{
    __shared__ float Prow[PK2];
    const int ne = blockIdx.x, n = ne >> 6, t = threadIdx.x;
    const float* docn = doc + (size_t)n * PL * PD;
    const float* mrow = map + (size_t)ne * PL;
    float mx0=-INFINITY, mx1=-INFINITY, mx2=-INFINITY, s0=0.f, s1=0.f, s2=0.f;
    bool has_zero = false;
    for (int l = 0; l < PL; ++l) {
        const float m = mrow[l];
        if (m != 0.0f) {
            const float* dr = docn + (size_t)l * PD;
            const float a = dr[t], c = dr[t+256], e = dr[t+512];
            mx0=fmaxf(mx0,a); s0+=a; mx1=fmaxf(mx1,c); s1+=c; mx2=fmaxf(mx2,e); s2+=e;
        } else has_zero = true;
    }
    if (has_zero) { mx0=fmaxf(mx0,0.f); mx1=fmaxf(mx1,0.f); mx2=fmaxf(mx2,0.f); }
    const float invlen = 1.0f / lens[ne];
    Prow[t]=mx0; Prow[t+256]=mx1; Prow[t+512]=mx2;
    Prow[PD+t]=s0*invlen; Prow[PD+t+256]=s1*invlen; Prow[PD+t+512]=s2*invlen;
    __syncthreads();
    #pragma unroll
    for (int i = 0; i < 3; ++i) {
        const int d = t + i*256;
        const float* wrow = W + (size_t)d * PK2;
        float acc = 0.f;
        for (int k = 0; k < PK2; k += 4) {
            const float4 w = *reinterpret_cast<const float4*>(&wrow[k]);
            acc += Prow[k]*w.x + Prow[k+1]*w.y + Prow[k+2]*w.z + Prow[k+3]*w.w;
        }
        out[(size_t)ne * PD + d] = acc + b[d];
    }
}

extern "C" void kernel_launch(void* const* d_in, const int* in_sizes, int n_in,
                              void* d_out, int out_size, void* d_ws, size_t ws_size,
                              hipStream_t stream) {
    const float* doc  = (const float*)d_in[0];   // (4,512,768)
    const float* map  = (const float*)d_in[1];   // (4,64,512)
    const float* lens = (const float*)d_in[2];   // (4,64)
    const float* W    = (const float*)d_in[3];   // (768,1536)
    const float* b    = (const float*)d_in[4];   // (768,)
    float* out = (float*)d_out;                  // (4,64,768)

    const size_t part_bytes = (size_t)PM * SPL * PD * sizeof(float);     // 6.0 MiB each
    const size_t pb_bytes   = (size_t)PM * PK2 * sizeof(unsigned short); // 768 KiB
    const size_t wb_bytes   = (size_t)PD * PK2 * sizeof(unsigned short); // 2.25 MiB
    const size_t need_new   = 2 * part_bytes + pb_bytes + wb_bytes;      // 15 MiB
    const size_t need_bf16  = pb_bytes + wb_bytes;                       // 3 MiB

    if (ws_size >= need_new) {
        float* Pmax = (float*)d_ws;
        float* Psum = (float*)((char*)d_ws + part_bytes);
        unsigned short* Pb = (unsigned short*)((char*)d_ws + 2 * part_bytes);
        unsigned short* Wb = (unsigned short*)((char*)d_ws + 2 * part_bytes + pb_bytes);
        // pool blocks (256) + W-convert blocks (576)
        pool_p1<<<dim3(PM + (PD * PK2) / (256 * 8)), dim3(256), 0, stream>>>(
            doc, map, W, Pmax, Psum, Wb);
        pool_p2<<<dim3(PM * PD / 256), dim3(256), 0, stream>>>(Pmax, Psum, lens, Pb);
        gemm_mfma<<<dim3((PM / 16) * (PD / 16)), dim3(64), 0, stream>>>(Pb, Wb, b, out);
    } else if (ws_size >= need_bf16) {
        unsigned short* Pb = (unsigned short*)d_ws;
        unsigned short* Wb = (unsigned short*)((char*)d_ws + pb_bytes);
        convert_w<<<dim3((PD * PK2) / (256 * 8)), dim3(256), 0, stream>>>(W, Wb);
        pool_kernel2<<<dim3(PM), dim3(1024), 0, stream>>>(doc, map, lens, Pb);
        gemm_mfma<<<dim3((PM / 16) * (PD / 16)), dim3(64), 0, stream>>>(Pb, Wb, b, out);
    } else {
        fused_kernel<<<dim3(PM), dim3(256), 0, stream>>>(doc, map, lens, W, b, out);
    }
}

// Round 4
// 32.762 us; speedup vs baseline: 4.7180x; 1.4586x over previous
//
#include <hip/hip_runtime.h>
#include <hip/hip_bf16.h>
#include <math.h>

// Problem constants: N=4, E=64, L=512, D=768
#define PN 4
#define PE 64
#define PL 512
#define PD 768
#define PK2 (2 * PD)        // 1536
#define PM (PN * PE)        // 256 rows

#define SPL 8               // L splits (chunks of 64)
#define EG  8               // entities per pool block
#define DC  3               // d-chunks of 256

using bf16x8 = __attribute__((ext_vector_type(8))) short;
using f32x4  = __attribute__((ext_vector_type(4))) float;

static __device__ __forceinline__ unsigned short f2bf(float x) {
    unsigned int u = __float_as_uint(x);
    unsigned int r = (u + 0x7FFFu + ((u >> 16) & 1u)) >> 16;   // RNE
    return (unsigned short)r;
}

// ---------------------------------------------------------------------------
// pool_p1 v2 (+ fused W->bf16 convert in extra blocks).
// Pool blocks (bid 0..767): (n, e-group of 8, L-chunk of 64, d-chunk of 256).
//   256 threads; thread owns ONE d = dc*256 + tid.
//   Mask chunk staged in LDS as smb[l][e] = {m, bias}; bias = m==0 ? -3e38 : 0
//   so masked max candidate = fma(m, v, bias)  (branch-free).
//   Per l-iter: 1 global load + 4 broadcast ds_read_b128 + 24 VALU.
//   Writes partial max/sum: Pmax/Psum [ne][s][d].
// Convert blocks (bid 768..1343): W f32 -> Wb bf16, 8 elems/thread.
// ---------------------------------------------------------------------------
__global__ __launch_bounds__(256) void pool_p1(
    const float* __restrict__ doc,    // [N][L][D]
    const float* __restrict__ map,    // [N][E][L]
    const float* __restrict__ W,      // [768][1536]
    float* __restrict__ Pmax,         // [256][8][768]
    float* __restrict__ Psum,         // [256][8][768]
    unsigned short* __restrict__ Wb)  // [768][1536] bf16
{
    const int bid = blockIdx.x;
    const int tid = threadIdx.x;

    if (bid >= PM * DC) {
        // ---- W conversion blocks ----
        const size_t i = ((size_t)(bid - PM * DC) * 256 + tid) * 8;
        const float4 a = *reinterpret_cast<const float4*>(W + i);
        const float4 c = *reinterpret_cast<const float4*>(W + i + 4);
        union { unsigned short s[8]; uint4 v; } r;
        r.s[0] = f2bf(a.x); r.s[1] = f2bf(a.y); r.s[2] = f2bf(a.z); r.s[3] = f2bf(a.w);
        r.s[4] = f2bf(c.x); r.s[5] = f2bf(c.y); r.s[6] = f2bf(c.z); r.s[7] = f2bf(c.w);
        *reinterpret_cast<uint4*>(Wb + i) = r.v;
        return;
    }

    __shared__ float2 smb[64][EG];    // [l][e] {m, bias} — 4 KB

    const int grp = bid / DC;         // (n, eg, s)
    const int dc  = bid - grp * DC;
    const int n   = grp >> 6;
    const int eg  = (grp >> 3) & 7;
    const int s   = grp & 7;
    const int e0  = eg * EG;
    const int l0  = s * 64;

    // stage mask chunk: 8 e x 64 l = 512 entries, 2 per thread
    #pragma unroll
    for (int i = 0; i < 2; ++i) {
        const int idx = tid + i * 256;
        const int l = idx >> 3, e = idx & 7;
        const float m = map[((size_t)n * PE + e0 + e) * PL + l0 + l];
        smb[l][e] = make_float2(m, (m == 0.0f) ? -3.0e38f : 0.0f);
    }
    __syncthreads();

    const float* docp = doc + ((size_t)n * PL + l0) * PD + dc * 256 + tid;

    float mx[EG], sm[EG];
    #pragma unroll
    for (int e = 0; e < EG; ++e) { mx[e] = -INFINITY; sm[e] = 0.f; }

    #pragma unroll 4
    for (int l = 0; l < 64; ++l) {
        const float v = docp[(size_t)l * PD];
        #pragma unroll
        for (int e = 0; e < EG; ++e) {
            const float2 mb = smb[l][e];
            sm[e] = fmaf(mb.x, v, sm[e]);
            mx[e] = fmaxf(mx[e], fmaf(mb.x, v, mb.y));
        }
    }

    #pragma unroll
    for (int e = 0; e < EG; ++e) {
        const size_t base = ((size_t)(n * PE + e0 + e) * SPL + s) * PD + dc * 256 + tid;
        Pmax[base] = mx[e];
        Psum[base] = sm[e];
    }
}

// ---------------------------------------------------------------------------
// pool_p2: fold 8 L-chunk partials -> Pb bf16 [256][1536] (max | mean).
// has_zero for entity (n,e) <=> lens < 512 (lens is exact mask sum, >=1).
// 768 blocks x 256 threads, one (ne,d) per thread.
// ---------------------------------------------------------------------------
__global__ __launch_bounds__(256) void pool_p2(
    const float* __restrict__ Pmax,
    const float* __restrict__ Psum,
    const float* __restrict__ lens,   // [256]
    unsigned short* __restrict__ Pb)  // [256][1536]
{
    const int idx = blockIdx.x * 256 + threadIdx.x;   // 0..196607
    const int ne = idx / PD;
    const int d  = idx - ne * PD;

    float mx = -INFINITY, smv = 0.f;
    #pragma unroll
    for (int s = 0; s < SPL; ++s) {
        const size_t o = ((size_t)ne * SPL + s) * PD + d;
        mx  = fmaxf(mx, Pmax[o]);
        smv += Psum[o];
    }
    const float ln = lens[ne];
    if (ln < 511.5f) mx = fmaxf(mx, 0.f);   // some mask entry is 0

    unsigned short* prow = Pb + (size_t)ne * PK2;
    prow[d]      = f2bf(mx);
    prow[PD + d] = f2bf(smv / ln);
}

// ---------------------------------------------------------------------------
// GEMM via MFMA bf16 16x16x32, no LDS. out[r][d] = sum_k P[r][k]*W[d][k] + b[d]
// 768 single-wave blocks, one 16x16 tile each.
// ---------------------------------------------------------------------------
__global__ __launch_bounds__(64) void gemm_mfma(
    const unsigned short* __restrict__ Pb,  // [256][1536] bf16
    const unsigned short* __restrict__ Wb,  // [768][1536] bf16
    const float* __restrict__ b,            // [768]
    float* __restrict__ out)                // [256][768]
{
    const int lane = threadIdx.x;
    const int tile = blockIdx.x;             // 0..767
    const int rt = tile & 15;                // M tile
    const int ct = tile >> 4;                // N tile
    const int r0 = rt * 16, d0 = ct * 16;

    const int fr = lane & 15;
    const int kg = lane >> 4;

    const unsigned short* pA = Pb + (size_t)(r0 + fr) * PK2 + kg * 8;
    const unsigned short* pB = Wb + (size_t)(d0 + fr) * PK2 + kg * 8;

    f32x4 acc = {0.f, 0.f, 0.f, 0.f};
    #pragma unroll 8
    for (int k0 = 0; k0 < PK2; k0 += 32) {
        const bf16x8 a  = *reinterpret_cast<const bf16x8*>(pA + k0);
        const bf16x8 bb = *reinterpret_cast<const bf16x8*>(pB + k0);
        acc = __builtin_amdgcn_mfma_f32_16x16x32_bf16(a, bb, acc, 0, 0, 0);
    }

    const int c = d0 + fr;
    const float bias = b[c];
    #pragma unroll
    for (int j = 0; j < 4; ++j)
        out[(size_t)(r0 + kg * 4 + j) * PD + c] = acc[j] + bias;
}

// ===========================================================================
// Fallback path (R2, proven): pool_kernel2 + convert_w + gemm_mfma (3 MiB ws)
// ===========================================================================
__global__ __launch_bounds__(256) void convert_w(
    const float* __restrict__ W, unsigned short* __restrict__ Wb)
{
    const size_t i = ((size_t)blockIdx.x * 256 + threadIdx.x) * 8;
    const float4 a = *reinterpret_cast<const float4*>(W + i);
    const float4 c = *reinterpret_cast<const float4*>(W + i + 4);
    union { unsigned short s[8]; uint4 v; } r;
    r.s[0] = f2bf(a.x); r.s[1] = f2bf(a.y); r.s[2] = f2bf(a.z); r.s[3] = f2bf(a.w);
    r.s[4] = f2bf(c.x); r.s[5] = f2bf(c.y); r.s[6] = f2bf(c.z); r.s[7] = f2bf(c.w);
    *reinterpret_cast<uint4*>(Wb + i) = r.v;
}

__global__ __launch_bounds__(1024) void pool_kernel2(
    const float* __restrict__ doc, const float* __restrict__ map,
    const float* __restrict__ lens, unsigned short* __restrict__ Pb)
{
    __shared__ float psum[4][PD];
    __shared__ float pmax[4][PD];
    __shared__ int   zf[4];
    const int ne = blockIdx.x, n = ne >> 6, t = threadIdx.x;
    const int g = t >> 8, td = t & 255;
    const float* docn = doc + (size_t)n * PL * PD;
    const float* mrow = map + (size_t)ne * PL;
    float mx0=-INFINITY, mx1=-INFINITY, mx2=-INFINITY, s0=0.f, s1=0.f, s2=0.f;
    bool hz = false;
    const int l0 = g * (PL/4), l1 = l0 + (PL/4);
    for (int l = l0; l < l1; ++l) {
        const float m = mrow[l];
        if (m != 0.0f) {
            const float* dr = docn + (size_t)l * PD;
            const float a = dr[td], c = dr[td+256], e = dr[td+512];
            mx0=fmaxf(mx0,a); s0+=a; mx1=fmaxf(mx1,c); s1+=c; mx2=fmaxf(mx2,e); s2+=e;
        } else hz = true;
    }
    psum[g][td]=s0; pmax[g][td]=mx0;
    psum[g][td+256]=s1; pmax[g][td+256]=mx1;
    psum[g][td+512]=s2; pmax[g][td+512]=mx2;
    if (td == 0) zf[g] = hz ? 1 : 0;
    __syncthreads();
    if (t < PD) {
        const float s = psum[0][t]+psum[1][t]+psum[2][t]+psum[3][t];
        float mx = fmaxf(fmaxf(pmax[0][t],pmax[1][t]), fmaxf(pmax[2][t],pmax[3][t]));
        if (zf[0]|zf[1]|zf[2]|zf[3]) mx = fmaxf(mx, 0.f);
        const float invlen = 1.0f / lens[ne];
        unsigned short* prow = Pb + (size_t)ne * PK2;
        prow[t]      = f2bf(mx);
        prow[PD + t] = f2bf(s * invlen);
    }
}

__global__ __launch_bounds__(256) void fused_kernel(
    const float* __restrict__ doc, const float* __restrict__ map,
    const float* __restrict__ lens, const float* __restrict__ W,
    const float* __restrict__ b, float* __restrict__ out)
{
    __shared__ float Prow[PK2];
    const int ne = blockIdx.x, n = ne >> 6, t = threadIdx.x;
    const float* docn = doc + (size_t)n * PL * PD;
    const float* mrow = map + (size_t)ne * PL;
    float mx0=-INFINITY, mx1=-INFINITY, mx2=-INFINITY, s0=0.f, s1=0.f, s2=0.f;
    bool has_zero = false;
    for (int l = 0; l < PL; ++l) {
        const float m = mrow[l];
        if (m != 0.0f) {
            const float* dr = docn + (size_t)l * PD;
            const float a = dr[t], c = dr[t+256], e = dr[t+512];
            mx0=fmaxf(mx0,a); s0+=a; mx1=fmaxf(mx1,c); s1+=c; mx2=fmaxf(mx2,e); s2+=e;
        } else has_zero = true;
    }
    if (has_zero) { mx0=fmaxf(mx0,0.f); mx1=fmaxf(mx1,0.f); mx2=fmaxf(mx2,0.f); }
    const float invlen = 1.0f / lens[ne];
    Prow[t]=mx0; Prow[t+256]=mx1; Prow[t+512]=mx2;
    Prow[PD+t]=s0*invlen; Prow[PD+t+256]=s1*invlen; Prow[PD+t+512]=s2*invlen;
    __syncthreads();
    #pragma unroll
    for (int i = 0; i < 3; ++i) {
        const int d = t + i*256;
        const float* wrow = W + (size_t)d * PK2;
        float acc = 0.f;
        for (int k = 0; k < PK2; k += 4) {
            const float4 w = *reinterpret_cast<const float4*>(&wrow[k]);
            acc += Prow[k]*w.x + Prow[k+1]*w.y + Prow[k+2]*w.z + Prow[k+3]*w.w;
        }
        out[(size_t)ne * PD + d] = acc + b[d];
    }
}

extern "C" void kernel_launch(void* const* d_in, const int* in_sizes, int n_in,
                              void* d_out, int out_size, void* d_ws, size_t ws_size,
                              hipStream_t stream) {
    const float* doc  = (const float*)d_in[0];   // (4,512,768)
    const float* map  = (const float*)d_in[1];   // (4,64,512)
    const float* lens = (const float*)d_in[2];   // (4,64)
    const float* W    = (const float*)d_in[3];   // (768,1536)
    const float* b    = (const float*)d_in[4];   // (768,)
    float* out = (float*)d_out;                  // (4,64,768)

    const size_t part_bytes = (size_t)PM * SPL * PD * sizeof(float);     // 6.0 MiB each
    const size_t pb_bytes   = (size_t)PM * PK2 * sizeof(unsigned short); // 768 KiB
    const size_t wb_bytes   = (size_t)PD * PK2 * sizeof(unsigned short); // 2.25 MiB
    const size_t need_new   = 2 * part_bytes + pb_bytes + wb_bytes;      // 15 MiB
    const size_t need_bf16  = pb_bytes + wb_bytes;                       // 3 MiB

    if (ws_size >= need_new) {
        float* Pmax = (float*)d_ws;
        float* Psum = (float*)((char*)d_ws + part_bytes);
        unsigned short* Pb = (unsigned short*)((char*)d_ws + 2 * part_bytes);
        unsigned short* Wb = (unsigned short*)((char*)d_ws + 2 * part_bytes + pb_bytes);
        // pool blocks (768) + W-convert blocks (576)
        pool_p1<<<dim3(PM * DC + (PD * PK2) / (256 * 8)), dim3(256), 0, stream>>>(
            doc, map, W, Pmax, Psum, Wb);
        pool_p2<<<dim3(PM * PD / 256), dim3(256), 0, stream>>>(Pmax, Psum, lens, Pb);
        gemm_mfma<<<dim3((PM / 16) * (PD / 16)), dim3(64), 0, stream>>>(Pb, Wb, b, out);
    } else if (ws_size >= need_bf16) {
        unsigned short* Pb = (unsigned short*)d_ws;
        unsigned short* Wb = (unsigned short*)((char*)d_ws + pb_bytes);
        convert_w<<<dim3((PD * PK2) / (256 * 8)), dim3(256), 0, stream>>>(W, Wb);
        pool_kernel2<<<dim3(PM), dim3(1024), 0, stream>>>(doc, map, lens, Pb);
        gemm_mfma<<<dim3((PM / 16) * (PD / 16)), dim3(64), 0, stream>>>(Pb, Wb, b, out);
    } else {
        fused_kernel<<<dim3(PM), dim3(256), 0, stream>>>(doc, map, lens, W, b, out);
    }
}